// Round 4
// baseline (1378.423 us; speedup 1.0000x reference)
//
#include <hip/hip_runtime.h>
#include <hip/hip_bf16.h>

#define BB   8
#define HGT  128
#define WID  128
#define CC   192
#define LLEN (HGT*WID)        // 16384
#define MM   (BB*LLEN)        // 131072
#define NF   388              // 2C + FL + 1
#define HIDN 768

typedef unsigned short us16;
typedef __attribute__((ext_vector_type(8))) short bf16x8;
typedef __attribute__((ext_vector_type(4))) float f32x4;

__device__ __forceinline__ float bf2f(us16 u) {
    return __uint_as_float(((unsigned int)u) << 16);
}
__device__ __forceinline__ us16 f2bf(float f) {
    unsigned int x = __float_as_uint(f);
    x = (x + 0x7fffu + ((x >> 16) & 1u)) >> 16;
    return (us16)x;
}
__device__ __forceinline__ float gelu_f(float x) {
    return 0.5f * x * (1.0f + erff(x * 0.70710678118654752f));
}

// ---------------- Weight convert: fp32 -> bf16, transposed ----------
__global__ __launch_bounds__(256) void wcvt_kernel(const float* __restrict__ f_w,
        const float* __restrict__ h_w, const float* __restrict__ proj_w,
        const float* __restrict__ fc1_w, const float* __restrict__ fc2_w,
        const float* __restrict__ fk0, const float* __restrict__ fk1,
        const float* __restrict__ fk2,
        us16* __restrict__ fwT, us16* __restrict__ hwB, us16* __restrict__ projT,
        us16* __restrict__ w1T, us16* __restrict__ w2T,
        us16* __restrict__ kw0T, us16* __restrict__ kw1T, us16* __restrict__ kw2T) {
    int i = blockIdx.x * 256 + threadIdx.x;
    if (i < 86016) {                       // fwT: 448 x 192 (pad rows >= 388 = 0)
        int n = i / 192, k = i % 192;
        fwT[i] = (n < NF) ? f2bf(f_w[k * NF + n]) : (us16)0;
        return;
    }
    i -= 86016;
    if (i < 36864) { hwB[i] = f2bf(h_w[i]); return; }       // h_w[o][c] is already [N][K]
    i -= 36864;
    if (i < 36864) { int n = i / 192, k = i % 192; projT[i] = f2bf(proj_w[k * CC + n]); return; }
    i -= 36864;
    if (i < 147456) { int n = i / 192, k = i % 192; w1T[i] = f2bf(fc1_w[k * HIDN + n]); return; }
    i -= 147456;
    if (i < 147456) { int n = i / 768, k = i % 768; w2T[i] = f2bf(fc2_w[k * CC + n]); return; }
    i -= 147456;
    if (i < 1728)  { int kyx = i / 192, c = i % 192; kw0T[i] = f2bf(fk0[c * 9 + kyx]);  return; }
    i -= 1728;
    if (i < 4800)  { int kyx = i / 192, c = i % 192; kw1T[i] = f2bf(fk1[c * 25 + kyx]); return; }
    i -= 4800;
    if (i < 9408)  { int kyx = i / 192, c = i % 192; kw2T[i] = f2bf(fk2[c * 49 + kyx]); return; }
}

// ---------------- LayerNorm: fp32 in -> bf16 out (wave per row) ----------------
__global__ __launch_bounds__(256) void ln_kernel(const float* __restrict__ in,
                                                 const float* __restrict__ g,
                                                 const float* __restrict__ b,
                                                 us16* __restrict__ out) {
    int wid  = threadIdx.x >> 6;
    int lane = threadIdx.x & 63;
    int row  = blockIdx.x * 4 + wid;
    const float* p = in + (size_t)row * CC;
    float v0 = p[lane], v1 = p[lane + 64], v2 = p[lane + 128];
    float s1 = v0 + v1 + v2;
    float s2 = v0*v0 + v1*v1 + v2*v2;
    for (int o = 32; o; o >>= 1) { s1 += __shfl_xor(s1, o); s2 += __shfl_xor(s2, o); }
    float m   = s1 * (1.0f / 192.0f);
    float var = s2 * (1.0f / 192.0f) - m * m;
    float inv = rsqrtf(var + 1e-5f);
    us16* q = out + (size_t)row * CC;
    q[lane]       = f2bf((v0 - m) * inv * g[lane]       + b[lane]);
    q[lane + 64]  = f2bf((v1 - m) * inv * g[lane + 64]  + b[lane + 64]);
    q[lane + 128] = f2bf((v2 - m) * inv * g[lane + 128] + b[lane + 128]);
}

// ---------------- MFMA GEMM: A(bf16 MxK=192) * Bt(bf16 [N][K]) ---------------
template<int MODE>
__global__ __launch_bounds__(256) void mgemm_kernel(const us16* __restrict__ A,
        const us16* __restrict__ Bt, const float* __restrict__ bias,
        us16* __restrict__ out_q, us16* __restrict__ out_ctx, us16* __restrict__ out_g,
        const us16* __restrict__ q_in, const us16* __restrict__ gates_in,
        const float* __restrict__ hg, const float* __restrict__ x_in,
        float* __restrict__ out_f) {
    constexpr int NT = (MODE == 0) ? 7 : 3;
    int id  = blockIdx.x;
    int xcd = id & 7;
    int s   = id >> 3;
    int mt  = xcd * 128 + s / NT;          // all N-tiles of an M-tile on one XCD
    int nt  = s % NT;
    int m0 = mt * 128, n0 = nt * 64;
    int tid = threadIdx.x, lane = tid & 63, w = tid >> 6;
    int wm = w >> 1, wn = w & 1, g = lane >> 4, lr = lane & 15;
    const us16* Ab = A  + (size_t)(m0 + wm * 64 + lr) * CC;
    const us16* Bb = Bt + (size_t)(n0 + wn * 32 + lr) * CC;
    f32x4 acc[4][2] = {};
    #pragma unroll
    for (int kk = 0; kk < 6; kk++) {
        int k = kk * 32 + g * 8;
        bf16x8 a0 = *(const bf16x8*)(Ab + 0 * 16 * CC + k);
        bf16x8 a1 = *(const bf16x8*)(Ab + 1 * 16 * CC + k);
        bf16x8 a2 = *(const bf16x8*)(Ab + 2 * 16 * CC + k);
        bf16x8 a3 = *(const bf16x8*)(Ab + 3 * 16 * CC + k);
        #pragma unroll
        for (int j = 0; j < 2; j++) {
            bf16x8 bv = *(const bf16x8*)(Bb + (size_t)j * 16 * CC + k);
            acc[0][j] = __builtin_amdgcn_mfma_f32_16x16x32_bf16(a0, bv, acc[0][j], 0, 0, 0);
            acc[1][j] = __builtin_amdgcn_mfma_f32_16x16x32_bf16(a1, bv, acc[1][j], 0, 0, 0);
            acc[2][j] = __builtin_amdgcn_mfma_f32_16x16x32_bf16(a2, bv, acc[2][j], 0, 0, 0);
            acc[3][j] = __builtin_amdgcn_mfma_f32_16x16x32_bf16(a3, bv, acc[3][j], 0, 0, 0);
        }
    }
    int orow = m0 + wm * 64;
    #pragma unroll
    for (int i = 0; i < 4; i++) {
        #pragma unroll
        for (int j = 0; j < 2; j++) {
            int ncol = n0 + wn * 32 + j * 16;
            int cc   = ncol + lr;
            #pragma unroll
            for (int r = 0; r < 4; r++) {
                int row = orow + i * 16 + g * 4 + r;
                float v = acc[i][j][r];
                if (MODE == 0) {
                    if (ncol < 192)      out_q[(size_t)row * CC + cc]          = f2bf(v + bias[cc]);
                    else if (ncol < 384) out_ctx[(size_t)row * CC + (cc - 192)] = f2bf(v + bias[cc]);
                    else if (cc < NF)    out_g[(size_t)row * 4 + (cc - 384)]    = f2bf(v + bias[cc]);
                } else if (MODE == 1) {
                    int bidx = row >> 14;
                    float val = v + bias[cc] + bf2f(gates_in[(size_t)row * 4 + 3]) * hg[bidx * CC + cc];
                    val *= bf2f(q_in[(size_t)row * CC + cc]);
                    out_q[(size_t)row * CC + cc] = f2bf(val);
                } else {
                    out_f[(size_t)row * CC + cc] = v + bias[cc] + x_in[(size_t)row * CC + cc];
                }
            }
        }
    }
}

// ---------------- Depthwise conv v2: 4 x-pixels x 8 channels per thread -------
template<int F, bool FIRST>
__global__ __launch_bounds__(256) void convv_kernel(const us16* __restrict__ in,
                            us16* __restrict__ outp,
                            us16* __restrict__ ctx_all,
                            const us16* __restrict__ gates,
                            const us16* __restrict__ kwT, int lvl) {
    constexpr int P  = F / 2;
    constexpr int NW = F + 3;          // row vectors per ky: XT + F - 1, XT = 4
    __shared__ __align__(16) us16 kws[F * F * CC];
    for (int t = threadIdx.x; t < F * F * CC / 8; t += 256)
        ((bf16x8*)kws)[t] = ((const bf16x8*)kwT)[t];
    __syncthreads();
    int idx  = blockIdx.x * 256 + threadIdx.x;   // over (MM/4)*24
    int cg   = idx % 24;
    int rest = idx / 24;                          // b*4096 + y*32 + x4
    int x4 = rest & 31;
    int y0 = (rest >> 5) & 127;
    int b  = rest >> 12;
    int x0 = x4 * 4;
    float acc[4][8] = {};
    const us16* inb = in + (size_t)b * LLEN * CC + cg * 8;
    for (int ky = 0; ky < F; ky++) {
        int yy = y0 + ky - P;
        if (yy < 0 || yy > 127) continue;
        const us16* rp = inb + (size_t)yy * WID * CC;
        float rv[NW][8];
        #pragma unroll
        for (int i = 0; i < NW; i++) {
            int xx = x0 - P + i;
            if (xx >= 0 && xx <= 127) {
                bf16x8 v = *(const bf16x8*)(rp + (size_t)xx * CC);
                #pragma unroll
                for (int j = 0; j < 8; j++) rv[i][j] = bf2f((us16)v[j]);
            } else {
                #pragma unroll
                for (int j = 0; j < 8; j++) rv[i][j] = 0.0f;
            }
        }
        #pragma unroll
        for (int kx = 0; kx < F; kx++) {
            bf16x8 wv = *(const bf16x8*)(kws + (ky * F + kx) * CC + cg * 8);
            float w[8];
            #pragma unroll
            for (int j = 0; j < 8; j++) w[j] = bf2f((us16)wv[j]);
            #pragma unroll
            for (int px = 0; px < 4; px++)
                #pragma unroll
                for (int j = 0; j < 8; j++)
                    acc[px][j] += rv[kx + px][j] * w[j];
        }
    }
    int pix = (b * HGT + y0) * WID + x0;
    size_t obase = (size_t)pix * CC + cg * 8;
    #pragma unroll
    for (int px = 0; px < 4; px++) {
        float gl = bf2f(gates[(size_t)(pix + px) * 4 + lvl]);
        bf16x8 cv;
        if (!FIRST) cv = *(const bf16x8*)(ctx_all + obase + (size_t)px * CC);
        bf16x8 ov, cs;
        #pragma unroll
        for (int j = 0; j < 8; j++) {
            float val = gelu_f(acc[px][j]);
            ov[j] = (short)f2bf(val);
            float contrib = val * gl + (FIRST ? 0.0f : bf2f((us16)cv[j]));
            cs[j] = (short)f2bf(contrib);
        }
        *(bf16x8*)(outp   + obase + (size_t)px * CC) = ov;
        *(bf16x8*)(ctx_all + obase + (size_t)px * CC) = cs;
    }
}

// ---------------- Global mean stage 1 ----------
__global__ __launch_bounds__(192) void gmean1_kernel(const us16* __restrict__ ctx,
                                                     float* __restrict__ partial) {
    int blk = blockIdx.x;           // 0..1023
    int b = blk >> 7, chunk = blk & 127;
    int c = threadIdx.x;
    size_t base = ((size_t)b * LLEN + (size_t)chunk * 128) * CC + c;
    float s = 0.0f;
    for (int p = 0; p < 128; p++) s += bf2f(ctx[base + (size_t)p * CC]);
    partial[(size_t)blk * CC + c] = s;
}

// ---------------- Global mean stage 2 + hg = h_w @ gelu(mean) ------------------
__global__ __launch_bounds__(256) void gmean2_kernel(const float* __restrict__ partial,
                                                     const float* __restrict__ h_w,
                                                     float* __restrict__ hg) {
    __shared__ float ctxg[BB * CC];
    for (int t = threadIdx.x; t < BB * CC; t += 256) {
        int b = t / CC, c = t % CC;
        float s = 0.0f;
        for (int p = 0; p < 128; p++) s += partial[(size_t)(b * 128 + p) * CC + c];
        ctxg[t] = gelu_f(s * (1.0f / 16384.0f));
    }
    __syncthreads();
    for (int t = threadIdx.x; t < BB * CC; t += 256) {
        int b = t / CC, o = t % CC;
        float s = 0.0f;
        for (int c2 = 0; c2 < CC; c2++) s += h_w[o * CC + c2] * ctxg[b * CC + c2];
        hg[t] = s;
    }
}

// ---------------- Fused LN2 + MLP v3: wave-private, weight-L1-shared ----------
// Block = 128 rows, 8 waves, wave owns 16 rows. Sweep hid in 32-col chunks:
// fc1 (swapped mfma) -> gelu -> per-wave LDS slab -> fc2 into persistent acc2.
#define MB2 128
__global__ __launch_bounds__(512, 4) void mlpf2_kernel(const float* __restrict__ x1,
        const float* __restrict__ ln2_g, const float* __restrict__ ln2_b,
        const us16* __restrict__ w1T, const float* __restrict__ fc1_b,
        const us16* __restrict__ w2T, const float* __restrict__ fc2_b,
        float* __restrict__ outp) {
    __shared__ us16 xb[8][3072];       // per-wave 16 rows x 384B, XOR (row&7)<<4
    __shared__ us16 slab[8][640];      // per-wave 16 rows x 80B stride
    __shared__ float b1s[HIDN];
    int tid = threadIdx.x, lane = tid & 63, w = tid >> 6;
    int g = lane >> 4, lr = lane & 15;
    int row0 = blockIdx.x * MB2 + w * 16;
    for (int t = tid; t < HIDN; t += 512) b1s[t] = fc1_b[t];
    __syncthreads();
    // ---- LN2 -> per-wave xb ----
    float gg0 = ln2_g[lane], gg1 = ln2_g[lane + 64], gg2 = ln2_g[lane + 128];
    float bb0 = ln2_b[lane], bb1 = ln2_b[lane + 64], bb2 = ln2_b[lane + 128];
    char* xbw = (char*)xb[w];
    for (int r = 0; r < 16; r++) {
        const float* p = x1 + (size_t)(row0 + r) * CC;
        float v0 = p[lane], v1 = p[lane + 64], v2 = p[lane + 128];
        float s1 = v0 + v1 + v2, s2 = v0*v0 + v1*v1 + v2*v2;
        for (int o = 32; o; o >>= 1) { s1 += __shfl_xor(s1, o); s2 += __shfl_xor(s2, o); }
        float m   = s1 * (1.0f / 192.0f);
        float inv = rsqrtf(s2 * (1.0f / 192.0f) - m * m + 1e-5f);
        int sw = (r & 7) << 4;
        *(us16*)(xbw + ((r * 384 + lane * 2)         ^ sw)) = f2bf((v0 - m) * inv * gg0 + bb0);
        *(us16*)(xbw + ((r * 384 + (lane + 64) * 2)  ^ sw)) = f2bf((v1 - m) * inv * gg1 + bb1);
        *(us16*)(xbw + ((r * 384 + (lane + 128) * 2) ^ sw)) = f2bf((v2 - m) * inv * gg2 + bb2);
    }
    // ---- x fragments: row lr, k = kk*32 + g*8, held in regs for all chunks ----
    bf16x8 xfr[6];
    {
        int sw = (lr & 7) << 4;
        #pragma unroll
        for (int kk = 0; kk < 6; kk++)
            xfr[kk] = *(const bf16x8*)(xbw + ((lr * 384 + (kk * 32 + g * 8) * 2) ^ sw));
    }
    us16* slabw = slab[w];
    f32x4 acc2[12] = {};
    for (int ch = 0; ch < 24; ch++) {
        int j0 = ch * 32;
        // fc1 (swapped): D[j = g*4+r (+16i)][m = lr]
        f32x4 acc1[2] = {};
        #pragma unroll
        for (int kk = 0; kk < 6; kk++) {
            int k = kk * 32 + g * 8;
            bf16x8 w1a = *(const bf16x8*)(w1T + (size_t)(j0 + lr) * CC + k);
            bf16x8 w1b = *(const bf16x8*)(w1T + (size_t)(j0 + 16 + lr) * CC + k);
            acc1[0] = __builtin_amdgcn_mfma_f32_16x16x32_bf16(w1a, xfr[kk], acc1[0], 0, 0, 0);
            acc1[1] = __builtin_amdgcn_mfma_f32_16x16x32_bf16(w1b, xfr[kk], acc1[1], 0, 0, 0);
        }
        // bias + gelu + pack to slab (row = lr, j linear within row, stride 80B)
        f32x4 bv0 = *(const f32x4*)(b1s + j0 + g * 4);
        f32x4 bv1 = *(const f32x4*)(b1s + j0 + 16 + g * 4);
        #pragma unroll
        for (int i = 0; i < 2; i++) {
            f32x4 bb = i ? bv1 : bv0;
            float h0 = gelu_f(acc1[i][0] + bb[0]);
            float h1 = gelu_f(acc1[i][1] + bb[1]);
            float h2 = gelu_f(acc1[i][2] + bb[2]);
            float h3 = gelu_f(acc1[i][3] + bb[3]);
            unsigned p0 = (unsigned)f2bf(h0) | ((unsigned)f2bf(h1) << 16);
            unsigned p1 = (unsigned)f2bf(h2) | ((unsigned)f2bf(h3) << 16);
            *(unsigned*)((char*)slabw + lr * 80 + i * 32 + g * 8)     = p0;
            *(unsigned*)((char*)slabw + lr * 80 + i * 32 + g * 8 + 4) = p1;
        }
        // fc2: a2 = hid[m=lr][j = g*8..g*8+7]; accumulate all 192 cols
        bf16x8 a2 = *(const bf16x8*)((char*)slabw + lr * 80 + g * 16);
        #pragma unroll
        for (int jj = 0; jj < 12; jj++) {
            bf16x8 b2 = *(const bf16x8*)(w2T + (size_t)(jj * 16 + lr) * HIDN + j0 + g * 8);
            acc2[jj] = __builtin_amdgcn_mfma_f32_16x16x32_bf16(a2, b2, acc2[jj], 0, 0, 0);
        }
    }
    // ---- epilogue: y + fc2_b + residual ----
    #pragma unroll
    for (int jj = 0; jj < 12; jj++) {
        int c = jj * 16 + lr;
        float fb = fc2_b[c];
        #pragma unroll
        for (int r = 0; r < 4; r++) {
            size_t o = (size_t)(row0 + g * 4 + r) * CC + c;
            outp[o] = acc2[jj][r] + fb + x1[o];
        }
    }
}

extern "C" void kernel_launch(void* const* d_in, const int* in_sizes, int n_in,
                              void* d_out, int out_size, void* d_ws, size_t ws_size,
                              hipStream_t stream) {
    const float* x      = (const float*)d_in[0];
    const float* ln1_g  = (const float*)d_in[1];
    const float* ln1_b  = (const float*)d_in[2];
    const float* f_w    = (const float*)d_in[3];
    const float* f_b    = (const float*)d_in[4];
    const float* fk0    = (const float*)d_in[5];
    const float* fk1    = (const float*)d_in[6];
    const float* fk2    = (const float*)d_in[7];
    const float* h_w    = (const float*)d_in[8];
    const float* h_b    = (const float*)d_in[9];
    const float* proj_w = (const float*)d_in[10];
    const float* proj_b = (const float*)d_in[11];
    const float* ln2_g  = (const float*)d_in[12];
    const float* ln2_b  = (const float*)d_in[13];
    const float* fc1_w  = (const float*)d_in[14];
    const float* fc1_b  = (const float*)d_in[15];
    const float* fc2_w  = (const float*)d_in[16];
    const float* fc2_b  = (const float*)d_in[17];
    float* outp = (float*)d_out;

    char* ws = (char*)d_ws;
    const size_t S = (size_t)MM * CC * 2;          // 50,331,648 B (one bf16 plane)
    us16* t_buf   = (us16*)(ws);                   // t / xq (reused)
    us16* q_buf   = (us16*)(ws + S);
    us16* ctx_all = (us16*)(ws + 2 * S);
    us16* gates   = (us16*)(ws + 3 * S);
    float* partial = (float*)(ws + 3 * S + 1048576);
    float* hg      = partial + 1024 * CC;
    us16* fwT   = (us16*)(ws + 3 * S + 1048576 + 786432 + 6144);
    us16* hwB   = fwT + 86016;
    us16* projT = hwB + 36864;
    us16* w1T   = projT + 36864;
    us16* w2T   = w1T + 147456;
    us16* kw0T  = w2T + 147456;
    us16* kw1T  = kw0T + 1728;
    us16* kw2T  = kw1T + 4800;
    // conv ping-pong lives in d_out (dead until proj rewrites it fully)
    us16* ctxA = (us16*)d_out;
    us16* ctxB = (us16*)d_out + (size_t)MM * CC;

    wcvt_kernel<<<1839, 256, 0, stream>>>(f_w, h_w, proj_w, fc1_w, fc2_w,
                                          fk0, fk1, fk2,
                                          fwT, hwB, projT, w1T, w2T, kw0T, kw1T, kw2T);

    ln_kernel<<<MM / 4, 256, 0, stream>>>(x, ln1_g, ln1_b, t_buf);

    mgemm_kernel<0><<<8 * 128 * 7, 256, 0, stream>>>(
        t_buf, fwT, f_b, q_buf, ctxA, gates, nullptr, nullptr, nullptr, nullptr, nullptr);

    const int convGrid = (MM / 4) * 24 / 256;      // 3072
    convv_kernel<3, true ><<<convGrid, 256, 0, stream>>>(ctxA, ctxB, ctx_all, gates, kw0T, 0);
    convv_kernel<5, false><<<convGrid, 256, 0, stream>>>(ctxB, ctxA, ctx_all, gates, kw1T, 1);
    convv_kernel<7, false><<<convGrid, 256, 0, stream>>>(ctxA, ctxB, ctx_all, gates, kw2T, 2);

    gmean1_kernel<<<1024, 192, 0, stream>>>(ctxB, partial);
    gmean2_kernel<<<1, 256, 0, stream>>>(partial, h_w, hg);

    mgemm_kernel<1><<<8 * 128 * 3, 256, 0, stream>>>(
        ctx_all, hwB, h_b, t_buf, nullptr, nullptr, q_buf, gates, hg, nullptr, nullptr);

    mgemm_kernel<2><<<8 * 128 * 3, 256, 0, stream>>>(
        t_buf, projT, proj_b, nullptr, nullptr, nullptr, nullptr, nullptr, nullptr, x, outp);

    mlpf2_kernel<<<MM / MB2, 512, 0, stream>>>(outp, ln2_g, ln2_b,
                                               w1T, fc1_b, w2T, fc2_b, outp);
}

// Round 5
// 1022.112 us; speedup vs baseline: 1.3486x; 1.3486x over previous
//
#include <hip/hip_runtime.h>
#include <hip/hip_bf16.h>

#define BB   8
#define HGT  128
#define WID  128
#define CC   192
#define LLEN (HGT*WID)        // 16384
#define MM   (BB*LLEN)        // 131072
#define NF   388              // 2C + FL + 1
#define HIDN 768

typedef unsigned short us16;
typedef __attribute__((ext_vector_type(8))) short bf16x8;
typedef __attribute__((ext_vector_type(4))) float f32x4;

__device__ __forceinline__ float bf2f(us16 u) {
    return __uint_as_float(((unsigned int)u) << 16);
}
__device__ __forceinline__ us16 f2bf(float f) {
    unsigned int x = __float_as_uint(f);
    x = (x + 0x7fffu + ((x >> 16) & 1u)) >> 16;
    return (us16)x;
}
// fast gelu: tanh form via exp2-backed __expf; |err| vs erf-form < ~3e-3 abs,
// negligible vs 0.1125 threshold after downstream small-weight GEMMs.
__device__ __forceinline__ float gelu_f(float x) {
    float u = 0.7978845608f * x * (1.0f + 0.044715f * x * x);
    float e = __expf(fminf(2.0f * u, 30.0f));    // clamp: avoid inf/inf
    return 0.5f * x * (1.0f + (e - 1.0f) / (e + 1.0f));
}

__device__ __forceinline__ void gload_lds16(const void* g, void* l) {
    __builtin_amdgcn_global_load_lds(
        (const __attribute__((address_space(1))) void*)g,
        (__attribute__((address_space(3))) void*)l, 16, 0, 0);
}

// ---------------- Weight convert: fp32 -> bf16, transposed ----------
__global__ __launch_bounds__(256) void wcvt_kernel(const float* __restrict__ f_w,
        const float* __restrict__ h_w, const float* __restrict__ proj_w,
        const float* __restrict__ fc1_w, const float* __restrict__ fc2_w,
        const float* __restrict__ fk0, const float* __restrict__ fk1,
        const float* __restrict__ fk2,
        us16* __restrict__ fwT, us16* __restrict__ hwB, us16* __restrict__ projT,
        us16* __restrict__ w1T, us16* __restrict__ w2T,
        us16* __restrict__ kw0T, us16* __restrict__ kw1T, us16* __restrict__ kw2T) {
    int i = blockIdx.x * 256 + threadIdx.x;
    if (i < 86016) {                       // fwT: 448 x 192 (pad rows >= 388 = 0)
        int n = i / 192, k = i % 192;
        fwT[i] = (n < NF) ? f2bf(f_w[k * NF + n]) : (us16)0;
        return;
    }
    i -= 86016;
    if (i < 36864) { hwB[i] = f2bf(h_w[i]); return; }       // h_w[o][c] is already [N][K]
    i -= 36864;
    if (i < 36864) { int n = i / 192, k = i % 192; projT[i] = f2bf(proj_w[k * CC + n]); return; }
    i -= 36864;
    if (i < 147456) { int n = i / 192, k = i % 192; w1T[i] = f2bf(fc1_w[k * HIDN + n]); return; }
    i -= 147456;
    if (i < 147456) { int n = i / 768, k = i % 768; w2T[i] = f2bf(fc2_w[k * CC + n]); return; }
    i -= 147456;
    if (i < 1728)  { int kyx = i / 192, c = i % 192; kw0T[i] = f2bf(fk0[c * 9 + kyx]);  return; }
    i -= 1728;
    if (i < 4800)  { int kyx = i / 192, c = i % 192; kw1T[i] = f2bf(fk1[c * 25 + kyx]); return; }
    i -= 4800;
    if (i < 9408)  { int kyx = i / 192, c = i % 192; kw2T[i] = f2bf(fk2[c * 49 + kyx]); return; }
}

// ---------------- LayerNorm: fp32 in -> bf16 out (wave per row) ----------------
__global__ __launch_bounds__(256) void ln_kernel(const float* __restrict__ in,
                                                 const float* __restrict__ g,
                                                 const float* __restrict__ b,
                                                 us16* __restrict__ out) {
    int wid  = threadIdx.x >> 6;
    int lane = threadIdx.x & 63;
    int row  = blockIdx.x * 4 + wid;
    const float* p = in + (size_t)row * CC;
    float v0 = p[lane], v1 = p[lane + 64], v2 = p[lane + 128];
    float s1 = v0 + v1 + v2;
    float s2 = v0*v0 + v1*v1 + v2*v2;
    for (int o = 32; o; o >>= 1) { s1 += __shfl_xor(s1, o); s2 += __shfl_xor(s2, o); }
    float m   = s1 * (1.0f / 192.0f);
    float var = s2 * (1.0f / 192.0f) - m * m;
    float inv = rsqrtf(var + 1e-5f);
    us16* q = out + (size_t)row * CC;
    q[lane]       = f2bf((v0 - m) * inv * g[lane]       + b[lane]);
    q[lane + 64]  = f2bf((v1 - m) * inv * g[lane + 64]  + b[lane + 64]);
    q[lane + 128] = f2bf((v2 - m) * inv * g[lane + 128] + b[lane + 128]);
}

// ---------------- MFMA GEMM v2: LDS-staged A (global_load_lds, swizzled src) --
// A tile 128x192 bf16 (48KB) staged async; B frags preloaded to VGPR before
// the barrier; compute loop is pure LDS ds_read + MFMA.
template<int MODE>
__global__ __launch_bounds__(256) void mgemm_kernel(const us16* __restrict__ A,
        const us16* __restrict__ Bt, const float* __restrict__ bias,
        us16* __restrict__ out_q, us16* __restrict__ out_ctx, us16* __restrict__ out_g,
        const us16* __restrict__ q_in, const us16* __restrict__ gates_in,
        const float* __restrict__ hg, const float* __restrict__ x_in,
        float* __restrict__ out_f) {
    __shared__ __align__(16) char Asm[128 * 384];
    constexpr int NT = (MODE == 0) ? 7 : 3;
    int id  = blockIdx.x;
    int xcd = id & 7;
    int s   = id >> 3;
    int mt  = xcd * 128 + s / NT;          // all N-tiles of an M-tile on one XCD
    int nt  = s % NT;
    int m0 = mt * 128, n0 = nt * 64;
    int tid = threadIdx.x, lane = tid & 63, w = tid >> 6;
    int wm = w >> 1, wn = w & 1, g = lane >> 4, lr = lane & 15;

    // ---- stage A tile: 48 wave-loads of 1KB, linear LDS dest, swizzled src ----
    const char* Agl = (const char*)(A + (size_t)m0 * CC);
    #pragma unroll
    for (int i = 0; i < 12; i++) {
        int wl   = w * 12 + i;                 // 0..47
        int byte = wl * 1024 + lane * 16;      // linear LDS byte this lane fills
        int row  = byte / 384;
        int off  = byte - row * 384;
        int soff = off ^ ((row & 7) << 4);     // pre-swizzled global source
        gload_lds16(Agl + (size_t)row * 384 + soff, Asm + wl * 1024);
    }

    // ---- preload all B fragments (overlaps async staging + barrier) ----
    const us16* Bb = Bt + (size_t)(n0 + wn * 32 + lr) * CC;
    bf16x8 bfr[6][2];
    #pragma unroll
    for (int kk = 0; kk < 6; kk++)
        #pragma unroll
        for (int j = 0; j < 2; j++)
            bfr[kk][j] = *(const bf16x8*)(Bb + (size_t)j * 16 * CC + kk * 32 + g * 8);

    __syncthreads();   // drains vmcnt (global_load_lds) before LDS reads

    f32x4 acc[4][2] = {};
    #pragma unroll
    for (int kk = 0; kk < 6; kk++) {
        int k2 = (kk * 32 + g * 8) * 2;
        bf16x8 a[4];
        #pragma unroll
        for (int i = 0; i < 4; i++) {
            int row = wm * 64 + i * 16 + lr;
            a[i] = *(const bf16x8*)(Asm + row * 384 + (k2 ^ ((row & 7) << 4)));
        }
        #pragma unroll
        for (int j = 0; j < 2; j++) {
            acc[0][j] = __builtin_amdgcn_mfma_f32_16x16x32_bf16(a[0], bfr[kk][j], acc[0][j], 0, 0, 0);
            acc[1][j] = __builtin_amdgcn_mfma_f32_16x16x32_bf16(a[1], bfr[kk][j], acc[1][j], 0, 0, 0);
            acc[2][j] = __builtin_amdgcn_mfma_f32_16x16x32_bf16(a[2], bfr[kk][j], acc[2][j], 0, 0, 0);
            acc[3][j] = __builtin_amdgcn_mfma_f32_16x16x32_bf16(a[3], bfr[kk][j], acc[3][j], 0, 0, 0);
        }
    }
    int orow = m0 + wm * 64;
    #pragma unroll
    for (int i = 0; i < 4; i++) {
        #pragma unroll
        for (int j = 0; j < 2; j++) {
            int ncol = n0 + wn * 32 + j * 16;
            int cc   = ncol + lr;
            #pragma unroll
            for (int r = 0; r < 4; r++) {
                int row = orow + i * 16 + g * 4 + r;
                float v = acc[i][j][r];
                if (MODE == 0) {
                    if (ncol < 192)      out_q[(size_t)row * CC + cc]          = f2bf(v + bias[cc]);
                    else if (ncol < 384) out_ctx[(size_t)row * CC + (cc - 192)] = f2bf(v + bias[cc]);
                    else if (cc < NF)    out_g[(size_t)row * 4 + (cc - 384)]    = f2bf(v + bias[cc]);
                } else if (MODE == 1) {
                    int bidx = row >> 14;
                    float val = v + bias[cc] + bf2f(gates_in[(size_t)row * 4 + 3]) * hg[bidx * CC + cc];
                    val *= bf2f(q_in[(size_t)row * CC + cc]);
                    out_q[(size_t)row * CC + cc] = f2bf(val);
                } else {
                    out_f[(size_t)row * CC + cc] = v + bias[cc] + x_in[(size_t)row * CC + cc];
                }
            }
        }
    }
}

// ---------------- Depthwise conv v2: 4 x-pixels x 8 channels per thread -------
template<int F, bool FIRST>
__global__ __launch_bounds__(256) void convv_kernel(const us16* __restrict__ in,
                            us16* __restrict__ outp,
                            us16* __restrict__ ctx_all,
                            const us16* __restrict__ gates,
                            const us16* __restrict__ kwT, int lvl) {
    constexpr int P  = F / 2;
    constexpr int NW = F + 3;          // row vectors per ky: XT + F - 1, XT = 4
    __shared__ __align__(16) us16 kws[F * F * CC];
    for (int t = threadIdx.x; t < F * F * CC / 8; t += 256)
        ((bf16x8*)kws)[t] = ((const bf16x8*)kwT)[t];
    __syncthreads();
    int idx  = blockIdx.x * 256 + threadIdx.x;   // over (MM/4)*24
    int cg   = idx % 24;
    int rest = idx / 24;                          // b*4096 + y*32 + x4
    int x4 = rest & 31;
    int y0 = (rest >> 5) & 127;
    int b  = rest >> 12;
    int x0 = x4 * 4;
    float acc[4][8] = {};
    const us16* inb = in + (size_t)b * LLEN * CC + cg * 8;
    for (int ky = 0; ky < F; ky++) {
        int yy = y0 + ky - P;
        if (yy < 0 || yy > 127) continue;
        const us16* rp = inb + (size_t)yy * WID * CC;
        float rv[NW][8];
        #pragma unroll
        for (int i = 0; i < NW; i++) {
            int xx = x0 - P + i;
            if (xx >= 0 && xx <= 127) {
                bf16x8 v = *(const bf16x8*)(rp + (size_t)xx * CC);
                #pragma unroll
                for (int j = 0; j < 8; j++) rv[i][j] = bf2f((us16)v[j]);
            } else {
                #pragma unroll
                for (int j = 0; j < 8; j++) rv[i][j] = 0.0f;
            }
        }
        #pragma unroll
        for (int kx = 0; kx < F; kx++) {
            bf16x8 wv = *(const bf16x8*)(kws + (ky * F + kx) * CC + cg * 8);
            float w[8];
            #pragma unroll
            for (int j = 0; j < 8; j++) w[j] = bf2f((us16)wv[j]);
            #pragma unroll
            for (int px = 0; px < 4; px++)
                #pragma unroll
                for (int j = 0; j < 8; j++)
                    acc[px][j] += rv[kx + px][j] * w[j];
        }
    }
    int pix = (b * HGT + y0) * WID + x0;
    size_t obase = (size_t)pix * CC + cg * 8;
    #pragma unroll
    for (int px = 0; px < 4; px++) {
        float gl = bf2f(gates[(size_t)(pix + px) * 4 + lvl]);
        bf16x8 cv;
        if (!FIRST) cv = *(const bf16x8*)(ctx_all + obase + (size_t)px * CC);
        bf16x8 ov, cs;
        #pragma unroll
        for (int j = 0; j < 8; j++) {
            float val = gelu_f(acc[px][j]);
            ov[j] = (short)f2bf(val);
            float contrib = val * gl + (FIRST ? 0.0f : bf2f((us16)cv[j]));
            cs[j] = (short)f2bf(contrib);
        }
        *(bf16x8*)(outp   + obase + (size_t)px * CC) = ov;
        *(bf16x8*)(ctx_all + obase + (size_t)px * CC) = cs;
    }
}

// ---------------- Global mean stage 1 ----------
__global__ __launch_bounds__(192) void gmean1_kernel(const us16* __restrict__ ctx,
                                                     float* __restrict__ partial) {
    int blk = blockIdx.x;           // 0..1023
    int b = blk >> 7, chunk = blk & 127;
    int c = threadIdx.x;
    size_t base = ((size_t)b * LLEN + (size_t)chunk * 128) * CC + c;
    float s = 0.0f;
    for (int p = 0; p < 128; p++) s += bf2f(ctx[base + (size_t)p * CC]);
    partial[(size_t)blk * CC + c] = s;
}

// ---------------- Global mean stage 2 + hg = h_w @ gelu(mean) ------------------
__global__ __launch_bounds__(256) void gmean2_kernel(const float* __restrict__ partial,
                                                     const float* __restrict__ h_w,
                                                     float* __restrict__ hg) {
    __shared__ float ctxg[BB * CC];
    for (int t = threadIdx.x; t < BB * CC; t += 256) {
        int b = t / CC, c = t % CC;
        float s = 0.0f;
        for (int p = 0; p < 128; p++) s += partial[(size_t)(b * 128 + p) * CC + c];
        ctxg[t] = gelu_f(s * (1.0f / 16384.0f));
    }
    __syncthreads();
    for (int t = threadIdx.x; t < BB * CC; t += 256) {
        int b = t / CC, o = t % CC;
        float s = 0.0f;
        for (int c2 = 0; c2 < CC; c2++) s += h_w[o * CC + c2] * ctxg[b * CC + c2];
        hg[t] = s;
    }
}

// ---------------- Fused LN2 + MLP (MFMA), in-place on d_out --------------------
// Round-3 structure (known-good), + fast gelu + VGPR headroom (512,4).
#define MB 32
__global__ __launch_bounds__(512, 4) void mlpf_kernel(const float* __restrict__ x1,
        const float* __restrict__ ln2_g, const float* __restrict__ ln2_b,
        const us16* __restrict__ w1T, const float* __restrict__ fc1_b,
        const us16* __restrict__ w2T, const float* __restrict__ fc2_b,
        float* __restrict__ outp) {
    __shared__ us16 xb[MB * CC];       // 12 KB, swizzled
    __shared__ us16 hid[MB * HIDN];    // 48 KB, swizzled
    int tid = threadIdx.x, lane = tid & 63, w = tid >> 6;
    int g = lane >> 4, lr = lane & 15;
    int m0 = blockIdx.x * MB;
    #pragma unroll
    for (int rr = 0; rr < 4; rr++) {
        int rb = w * 4 + rr;
        const float* p = x1 + (size_t)(m0 + rb) * CC;
        float v0 = p[lane], v1 = p[lane + 64], v2 = p[lane + 128];
        float s1 = v0 + v1 + v2, s2 = v0*v0 + v1*v1 + v2*v2;
        for (int o = 32; o; o >>= 1) { s1 += __shfl_xor(s1, o); s2 += __shfl_xor(s2, o); }
        float m   = s1 * (1.0f / 192.0f);
        float inv = rsqrtf(s2 * (1.0f / 192.0f) - m * m + 1e-5f);
        int sw = (rb & 7) << 4;
        char* base = (char*)xb;
        *(us16*)(base + ((rb * 384 + lane * 2)         ^ sw)) = f2bf((v0 - m) * inv * ln2_g[lane]       + ln2_b[lane]);
        *(us16*)(base + ((rb * 384 + (lane + 64) * 2)  ^ sw)) = f2bf((v1 - m) * inv * ln2_g[lane + 64]  + ln2_b[lane + 64]);
        *(us16*)(base + ((rb * 384 + (lane + 128) * 2) ^ sw)) = f2bf((v2 - m) * inv * ln2_g[lane + 128] + ln2_b[lane + 128]);
    }
    __syncthreads();
    {
        f32x4 acc[2][6] = {};
        int nb = w * 96;
        int swA = (lr & 7) << 4;
        #pragma unroll
        for (int kk = 0; kk < 6; kk++) {
            int k = kk * 32 + g * 8;
            bf16x8 a0 = *(const bf16x8*)((char*)xb + ((lr * 384 + k * 2) ^ swA));
            bf16x8 a1 = *(const bf16x8*)((char*)xb + (((lr + 16) * 384 + k * 2) ^ swA));
            #pragma unroll
            for (int j = 0; j < 6; j++) {
                bf16x8 bv = *(const bf16x8*)(w1T + (size_t)(nb + j * 16 + lr) * CC + k);
                acc[0][j] = __builtin_amdgcn_mfma_f32_16x16x32_bf16(a0, bv, acc[0][j], 0, 0, 0);
                acc[1][j] = __builtin_amdgcn_mfma_f32_16x16x32_bf16(a1, bv, acc[1][j], 0, 0, 0);
            }
        }
        #pragma unroll
        for (int j = 0; j < 6; j++) {
            int n = nb + j * 16 + lr;
            float bias = fc1_b[n];
            #pragma unroll
            for (int i = 0; i < 2; i++) {
                #pragma unroll
                for (int r = 0; r < 4; r++) {
                    int mrow = i * 16 + g * 4 + r;
                    float val = gelu_f(acc[i][j][r] + bias);
                    *(us16*)((char*)hid + ((mrow * 1536 + n * 2) ^ ((mrow & 7) << 4))) = f2bf(val);
                }
            }
        }
    }
    __syncthreads();
    {
        int wm = w >> 2, wn = w & 3;
        f32x4 acc[3] = {};
        int row = wm * 16 + lr;
        int sw  = (row & 7) << 4;
        #pragma unroll 4
        for (int kk = 0; kk < 24; kk++) {
            int k = kk * 32 + g * 8;
            bf16x8 a = *(const bf16x8*)((char*)hid + ((row * 1536 + k * 2) ^ sw));
            #pragma unroll
            for (int j = 0; j < 3; j++) {
                bf16x8 bv = *(const bf16x8*)(w2T + (size_t)(wn * 48 + j * 16 + lr) * HIDN + k);
                acc[j] = __builtin_amdgcn_mfma_f32_16x16x32_bf16(a, bv, acc[j], 0, 0, 0);
            }
        }
        #pragma unroll
        for (int j = 0; j < 3; j++) {
            int col = wn * 48 + j * 16 + lr;
            float bias = fc2_b[col];
            #pragma unroll
            for (int r = 0; r < 4; r++) {
                int grow = m0 + wm * 16 + g * 4 + r;
                outp[(size_t)grow * CC + col] = acc[j][r] + bias + x1[(size_t)grow * CC + col];
            }
        }
    }
}

extern "C" void kernel_launch(void* const* d_in, const int* in_sizes, int n_in,
                              void* d_out, int out_size, void* d_ws, size_t ws_size,
                              hipStream_t stream) {
    const float* x      = (const float*)d_in[0];
    const float* ln1_g  = (const float*)d_in[1];
    const float* ln1_b  = (const float*)d_in[2];
    const float* f_w    = (const float*)d_in[3];
    const float* f_b    = (const float*)d_in[4];
    const float* fk0    = (const float*)d_in[5];
    const float* fk1    = (const float*)d_in[6];
    const float* fk2    = (const float*)d_in[7];
    const float* h_w    = (const float*)d_in[8];
    const float* h_b    = (const float*)d_in[9];
    const float* proj_w = (const float*)d_in[10];
    const float* proj_b = (const float*)d_in[11];
    const float* ln2_g  = (const float*)d_in[12];
    const float* ln2_b  = (const float*)d_in[13];
    const float* fc1_w  = (const float*)d_in[14];
    const float* fc1_b  = (const float*)d_in[15];
    const float* fc2_w  = (const float*)d_in[16];
    const float* fc2_b  = (const float*)d_in[17];
    float* outp = (float*)d_out;

    char* ws = (char*)d_ws;
    const size_t S = (size_t)MM * CC * 2;          // 50,331,648 B (one bf16 plane)
    us16* t_buf   = (us16*)(ws);                   // t / xq (reused)
    us16* q_buf   = (us16*)(ws + S);
    us16* ctx_all = (us16*)(ws + 2 * S);
    us16* gates   = (us16*)(ws + 3 * S);
    float* partial = (float*)(ws + 3 * S + 1048576);
    float* hg      = partial + 1024 * CC;
    us16* fwT   = (us16*)(ws + 3 * S + 1048576 + 786432 + 6144);
    us16* hwB   = fwT + 86016;
    us16* projT = hwB + 36864;
    us16* w1T   = projT + 36864;
    us16* w2T   = w1T + 147456;
    us16* kw0T  = w2T + 147456;
    us16* kw1T  = kw0T + 1728;
    us16* kw2T  = kw1T + 4800;
    // conv ping-pong lives in d_out (dead until proj rewrites it fully)
    us16* ctxA = (us16*)d_out;
    us16* ctxB = (us16*)d_out + (size_t)MM * CC;

    wcvt_kernel<<<1839, 256, 0, stream>>>(f_w, h_w, proj_w, fc1_w, fc2_w,
                                          fk0, fk1, fk2,
                                          fwT, hwB, projT, w1T, w2T, kw0T, kw1T, kw2T);

    ln_kernel<<<MM / 4, 256, 0, stream>>>(x, ln1_g, ln1_b, t_buf);

    mgemm_kernel<0><<<8 * 128 * 7, 256, 0, stream>>>(
        t_buf, fwT, f_b, q_buf, ctxA, gates, nullptr, nullptr, nullptr, nullptr, nullptr);

    const int convGrid = (MM / 4) * 24 / 256;      // 3072
    convv_kernel<3, true ><<<convGrid, 256, 0, stream>>>(ctxA, ctxB, ctx_all, gates, kw0T, 0);
    convv_kernel<5, false><<<convGrid, 256, 0, stream>>>(ctxB, ctxA, ctx_all, gates, kw1T, 1);
    convv_kernel<7, false><<<convGrid, 256, 0, stream>>>(ctxA, ctxB, ctx_all, gates, kw2T, 2);

    gmean1_kernel<<<1024, 192, 0, stream>>>(ctxB, partial);
    gmean2_kernel<<<1, 256, 0, stream>>>(partial, h_w, hg);

    mgemm_kernel<1><<<8 * 128 * 3, 256, 0, stream>>>(
        ctx_all, hwB, h_b, t_buf, nullptr, nullptr, q_buf, gates, hg, nullptr, nullptr);

    mgemm_kernel<2><<<8 * 128 * 3, 256, 0, stream>>>(
        t_buf, projT, proj_b, nullptr, nullptr, nullptr, nullptr, nullptr, nullptr, x, outp);

    mlpf_kernel<<<MM / MB, 512, 0, stream>>>(outp, ln2_g, ln2_b,
                                             w1T, fc1_b, w2T, fc2_b, outp);
}

// Round 6
// 837.206 us; speedup vs baseline: 1.6465x; 1.2209x over previous
//
#include <hip/hip_runtime.h>
#include <hip/hip_bf16.h>

#define BB   8
#define HGT  128
#define WID  128
#define CC   192
#define LLEN (HGT*WID)        // 16384
#define MM   (BB*LLEN)        // 131072
#define NF   388              // 2C + FL + 1
#define HIDN 768

typedef unsigned short us16;
typedef __attribute__((ext_vector_type(8))) short bf16x8;
typedef __attribute__((ext_vector_type(4))) float f32x4;

__device__ __forceinline__ float bf2f(us16 u) {
    return __uint_as_float(((unsigned int)u) << 16);
}
__device__ __forceinline__ us16 f2bf(float f) {
    unsigned int x = __float_as_uint(f);
    x = (x + 0x7fffu + ((x >> 16) & 1u)) >> 16;
    return (us16)x;
}
// fast gelu: tanh form via exp2-backed __expf
__device__ __forceinline__ float gelu_f(float x) {
    float u = 0.7978845608f * x * (1.0f + 0.044715f * x * x);
    float e = __expf(fminf(2.0f * u, 30.0f));
    return 0.5f * x * (1.0f + (e - 1.0f) / (e + 1.0f));
}

__device__ __forceinline__ void gload_lds16(const void* g, void* l) {
    __builtin_amdgcn_global_load_lds(
        (const __attribute__((address_space(1))) void*)g,
        (__attribute__((address_space(3))) void*)l, 16, 0, 0);
}

// ---------------- Weight convert: fp32 -> bf16, transposed ----------
__global__ __launch_bounds__(256) void wcvt_kernel(const float* __restrict__ f_w,
        const float* __restrict__ h_w, const float* __restrict__ proj_w,
        const float* __restrict__ fc1_w, const float* __restrict__ fc2_w,
        const float* __restrict__ fk0, const float* __restrict__ fk1,
        const float* __restrict__ fk2,
        us16* __restrict__ fwT, us16* __restrict__ hwB, us16* __restrict__ projT,
        us16* __restrict__ w1T, us16* __restrict__ w2T,
        us16* __restrict__ kw0T, us16* __restrict__ kw1T, us16* __restrict__ kw2T) {
    int i = blockIdx.x * 256 + threadIdx.x;
    if (i < 86016) {                       // fwT: 448 x 192 (pad rows >= 388 = 0)
        int n = i / 192, k = i % 192;
        fwT[i] = (n < NF) ? f2bf(f_w[k * NF + n]) : (us16)0;
        return;
    }
    i -= 86016;
    if (i < 36864) { hwB[i] = f2bf(h_w[i]); return; }       // h_w[o][c] is already [N][K]
    i -= 36864;
    if (i < 36864) { int n = i / 192, k = i % 192; projT[i] = f2bf(proj_w[k * CC + n]); return; }
    i -= 36864;
    if (i < 147456) { int n = i / 192, k = i % 192; w1T[i] = f2bf(fc1_w[k * HIDN + n]); return; }
    i -= 147456;
    if (i < 147456) { int n = i / 768, k = i % 768; w2T[i] = f2bf(fc2_w[k * CC + n]); return; }
    i -= 147456;
    if (i < 1728)  { int kyx = i / 192, c = i % 192; kw0T[i] = f2bf(fk0[c * 9 + kyx]);  return; }
    i -= 1728;
    if (i < 4800)  { int kyx = i / 192, c = i % 192; kw1T[i] = f2bf(fk1[c * 25 + kyx]); return; }
    i -= 4800;
    if (i < 9408)  { int kyx = i / 192, c = i % 192; kw2T[i] = f2bf(fk2[c * 49 + kyx]); return; }
}

// ---------------- LayerNorm: fp32 in -> bf16 out (wave per row) ----------------
__global__ __launch_bounds__(256) void ln_kernel(const float* __restrict__ in,
                                                 const float* __restrict__ g,
                                                 const float* __restrict__ b,
                                                 us16* __restrict__ out) {
    int wid  = threadIdx.x >> 6;
    int lane = threadIdx.x & 63;
    int row  = blockIdx.x * 4 + wid;
    const float* p = in + (size_t)row * CC;
    float v0 = p[lane], v1 = p[lane + 64], v2 = p[lane + 128];
    float s1 = v0 + v1 + v2;
    float s2 = v0*v0 + v1*v1 + v2*v2;
    for (int o = 32; o; o >>= 1) { s1 += __shfl_xor(s1, o); s2 += __shfl_xor(s2, o); }
    float m   = s1 * (1.0f / 192.0f);
    float var = s2 * (1.0f / 192.0f) - m * m;
    float inv = rsqrtf(var + 1e-5f);
    us16* q = out + (size_t)row * CC;
    q[lane]       = f2bf((v0 - m) * inv * g[lane]       + b[lane]);
    q[lane + 64]  = f2bf((v1 - m) * inv * g[lane + 64]  + b[lane + 64]);
    q[lane + 128] = f2bf((v2 - m) * inv * g[lane + 128] + b[lane + 128]);
}

// ---------------- MFMA GEMM: LDS-staged A, K=192, 128x64 tile, 4 waves --------
template<int MODE>
__global__ __launch_bounds__(256) void mgemm_kernel(const us16* __restrict__ A,
        const us16* __restrict__ Bt, const float* __restrict__ bias,
        us16* __restrict__ out_q, us16* __restrict__ out_ctx, us16* __restrict__ out_g,
        const us16* __restrict__ q_in, const us16* __restrict__ gates_in,
        const float* __restrict__ hg, const float* __restrict__ x_in,
        float* __restrict__ out_f) {
    __shared__ __align__(16) char Asm[128 * 384];
    constexpr int NT = (MODE == 0) ? 7 : 3;
    int id  = blockIdx.x;
    int xcd = id & 7;
    int s   = id >> 3;
    int mt  = xcd * 128 + s / NT;          // all N-tiles of an M-tile on one XCD
    int nt  = s % NT;
    int m0 = mt * 128, n0 = nt * 64;
    int tid = threadIdx.x, lane = tid & 63, w = tid >> 6;
    int wm = w >> 1, wn = w & 1, g = lane >> 4, lr = lane & 15;

    const char* Agl = (const char*)(A + (size_t)m0 * CC);
    #pragma unroll
    for (int i = 0; i < 12; i++) {
        int wl   = w * 12 + i;                 // 0..47
        int byte = wl * 1024 + lane * 16;
        int row  = byte / 384;
        int off  = byte - row * 384;
        int soff = off ^ ((row & 7) << 4);
        gload_lds16(Agl + (size_t)row * 384 + soff, Asm + wl * 1024);
    }
    const us16* Bb = Bt + (size_t)(n0 + wn * 32 + lr) * CC;
    bf16x8 bfr[6][2];
    #pragma unroll
    for (int kk = 0; kk < 6; kk++)
        #pragma unroll
        for (int j = 0; j < 2; j++)
            bfr[kk][j] = *(const bf16x8*)(Bb + (size_t)j * 16 * CC + kk * 32 + g * 8);

    __syncthreads();

    f32x4 acc[4][2] = {};
    #pragma unroll
    for (int kk = 0; kk < 6; kk++) {
        int k2 = (kk * 32 + g * 8) * 2;
        bf16x8 a[4];
        #pragma unroll
        for (int i = 0; i < 4; i++) {
            int row = wm * 64 + i * 16 + lr;
            a[i] = *(const bf16x8*)(Asm + row * 384 + (k2 ^ ((row & 7) << 4)));
        }
        #pragma unroll
        for (int j = 0; j < 2; j++) {
            acc[0][j] = __builtin_amdgcn_mfma_f32_16x16x32_bf16(a[0], bfr[kk][j], acc[0][j], 0, 0, 0);
            acc[1][j] = __builtin_amdgcn_mfma_f32_16x16x32_bf16(a[1], bfr[kk][j], acc[1][j], 0, 0, 0);
            acc[2][j] = __builtin_amdgcn_mfma_f32_16x16x32_bf16(a[2], bfr[kk][j], acc[2][j], 0, 0, 0);
            acc[3][j] = __builtin_amdgcn_mfma_f32_16x16x32_bf16(a[3], bfr[kk][j], acc[3][j], 0, 0, 0);
        }
    }
    int orow = m0 + wm * 64;
    #pragma unroll
    for (int i = 0; i < 4; i++) {
        #pragma unroll
        for (int j = 0; j < 2; j++) {
            int ncol = n0 + wn * 32 + j * 16;
            int cc   = ncol + lr;
            #pragma unroll
            for (int r = 0; r < 4; r++) {
                int row = orow + i * 16 + g * 4 + r;
                float v = acc[i][j][r];
                if (MODE == 0) {
                    if (ncol < 192)      out_q[(size_t)row * CC + cc]          = f2bf(v + bias[cc]);
                    else if (ncol < 384) out_ctx[(size_t)row * CC + (cc - 192)] = f2bf(v + bias[cc]);
                    else if (cc < NF)    out_g[(size_t)row * 4 + (cc - 384)]    = f2bf(v + bias[cc]);
                } else if (MODE == 1) {
                    int bidx = row >> 14;
                    float val = v + bias[cc] + bf2f(gates_in[(size_t)row * 4 + 3]) * hg[bidx * CC + cc];
                    val *= bf2f(q_in[(size_t)row * CC + cc]);
                    out_q[(size_t)row * CC + cc] = f2bf(val);
                } else {
                    out_f[(size_t)row * CC + cc] = v + bias[cc] + x_in[(size_t)row * CC + cc];
                }
            }
        }
    }
}

// ---------------- fc1: hid = gelu(ln2 @ w1 + b1), 128x128 tile, 8 waves -------
__global__ __launch_bounds__(512, 4) void fc1_kernel(const us16* __restrict__ A,
        const us16* __restrict__ w1T, const float* __restrict__ bias,
        us16* __restrict__ hid0, us16* __restrict__ hid1) {
    __shared__ __align__(16) char Asm[128 * 384];
    int m0 = blockIdx.x * 128;
    int n0 = blockIdx.y * 128;
    int tid = threadIdx.x, lane = tid & 63, w = tid >> 6;
    int wm = w >> 2, wn = w & 3, g = lane >> 4, lr = lane & 15;

    const char* Agl = (const char*)(A + (size_t)m0 * CC);
    #pragma unroll
    for (int i = 0; i < 6; i++) {
        int wl   = w * 6 + i;                  // 0..47
        int byte = wl * 1024 + lane * 16;
        int row  = byte / 384;
        int off  = byte - row * 384;
        int soff = off ^ ((row & 7) << 4);
        gload_lds16(Agl + (size_t)row * 384 + soff, Asm + wl * 1024);
    }
    const us16* Bb = w1T + (size_t)(n0 + wn * 32 + lr) * CC;
    bf16x8 bfr[6][2];
    #pragma unroll
    for (int kk = 0; kk < 6; kk++)
        #pragma unroll
        for (int j = 0; j < 2; j++)
            bfr[kk][j] = *(const bf16x8*)(Bb + (size_t)j * 16 * CC + kk * 32 + g * 8);

    __syncthreads();

    f32x4 acc[4][2] = {};
    #pragma unroll
    for (int kk = 0; kk < 6; kk++) {
        int k2 = (kk * 32 + g * 8) * 2;
        bf16x8 a[4];
        #pragma unroll
        for (int i = 0; i < 4; i++) {
            int row = wm * 64 + i * 16 + lr;
            a[i] = *(const bf16x8*)(Asm + row * 384 + (k2 ^ ((row & 7) << 4)));
        }
        #pragma unroll
        for (int j = 0; j < 2; j++) {
            acc[0][j] = __builtin_amdgcn_mfma_f32_16x16x32_bf16(a[0], bfr[kk][j], acc[0][j], 0, 0, 0);
            acc[1][j] = __builtin_amdgcn_mfma_f32_16x16x32_bf16(a[1], bfr[kk][j], acc[1][j], 0, 0, 0);
            acc[2][j] = __builtin_amdgcn_mfma_f32_16x16x32_bf16(a[2], bfr[kk][j], acc[2][j], 0, 0, 0);
            acc[3][j] = __builtin_amdgcn_mfma_f32_16x16x32_bf16(a[3], bfr[kk][j], acc[3][j], 0, 0, 0);
        }
    }
    us16* hidp = (m0 & 32768) ? hid1 : hid0;
    int ml = (m0 & 32767) + wm * 64;
    #pragma unroll
    for (int i = 0; i < 4; i++) {
        #pragma unroll
        for (int j = 0; j < 2; j++) {
            int col = n0 + wn * 32 + j * 16 + lr;
            float fb = bias[col];
            #pragma unroll
            for (int r = 0; r < 4; r++) {
                int row = ml + i * 16 + g * 4 + r;
                hidp[(size_t)row * HIDN + col] = f2bf(gelu_f(acc[i][j][r] + fb));
            }
        }
    }
}

// ---------------- fc2: out += hid @ w2 + b2, 128x192 tile, K=768 in 4 chunks --
__global__ __launch_bounds__(512, 4) void fc2_kernel(const us16* __restrict__ hid0,
        const us16* __restrict__ hid1, const us16* __restrict__ w2T,
        const float* __restrict__ bias, float* __restrict__ io) {
    __shared__ __align__(16) char Asm[128 * 384];
    int m0 = blockIdx.x * 128;
    int tid = threadIdx.x, lane = tid & 63, w = tid >> 6;
    int wm = w >> 2, wn = w & 3, g = lane >> 4, lr = lane & 15;
    const us16* hidp = (m0 & 32768) ? hid1 : hid0;
    const char* Agl = (const char*)(hidp + (size_t)(m0 & 32767) * HIDN);

    f32x4 acc[4][3] = {};
    for (int c = 0; c < 4; c++) {
        #pragma unroll
        for (int i = 0; i < 6; i++) {
            int wl   = w * 6 + i;
            int byte = wl * 1024 + lane * 16;
            int row  = byte / 384;
            int off  = byte - row * 384;
            int soff = off ^ ((row & 7) << 4);
            gload_lds16(Agl + (size_t)row * 1536 + c * 384 + soff, Asm + wl * 1024);
        }
        __syncthreads();                       // DMA drained (vmcnt 0)
        #pragma unroll
        for (int kk = 0; kk < 6; kk++) {
            int k2 = (kk * 32 + g * 8) * 2;
            bf16x8 a[4];
            #pragma unroll
            for (int i = 0; i < 4; i++) {
                int row = wm * 64 + i * 16 + lr;
                a[i] = *(const bf16x8*)(Asm + row * 384 + (k2 ^ ((row & 7) << 4)));
            }
            #pragma unroll
            for (int j = 0; j < 3; j++) {
                bf16x8 bv = *(const bf16x8*)(w2T + (size_t)(wn * 48 + j * 16 + lr) * HIDN
                                             + c * 192 + kk * 32 + g * 8);
                acc[0][j] = __builtin_amdgcn_mfma_f32_16x16x32_bf16(a[0], bv, acc[0][j], 0, 0, 0);
                acc[1][j] = __builtin_amdgcn_mfma_f32_16x16x32_bf16(a[1], bv, acc[1][j], 0, 0, 0);
                acc[2][j] = __builtin_amdgcn_mfma_f32_16x16x32_bf16(a[2], bv, acc[2][j], 0, 0, 0);
                acc[3][j] = __builtin_amdgcn_mfma_f32_16x16x32_bf16(a[3], bv, acc[3][j], 0, 0, 0);
            }
        }
        __syncthreads();                       // safe to overwrite Asm
    }
    #pragma unroll
    for (int i = 0; i < 4; i++) {
        #pragma unroll
        for (int j = 0; j < 3; j++) {
            int col = wn * 48 + j * 16 + lr;
            float fb = bias[col];
            #pragma unroll
            for (int r = 0; r < 4; r++) {
                int row = m0 + wm * 64 + i * 16 + g * 4 + r;
                io[(size_t)row * CC + col] += acc[i][j][r] + fb;
            }
        }
    }
}

// ---------------- Depthwise conv v2: 4 x-pixels x 8 channels per thread -------
template<int F, bool FIRST>
__global__ __launch_bounds__(256) void convv_kernel(const us16* __restrict__ in,
                            us16* __restrict__ outp,
                            us16* __restrict__ ctx_all,
                            const us16* __restrict__ gates,
                            const us16* __restrict__ kwT, int lvl) {
    constexpr int P  = F / 2;
    constexpr int NW = F + 3;          // row vectors per ky: XT + F - 1, XT = 4
    __shared__ __align__(16) us16 kws[F * F * CC];
    for (int t = threadIdx.x; t < F * F * CC / 8; t += 256)
        ((bf16x8*)kws)[t] = ((const bf16x8*)kwT)[t];
    __syncthreads();
    int idx  = blockIdx.x * 256 + threadIdx.x;   // over (MM/4)*24
    int cg   = idx % 24;
    int rest = idx / 24;                          // b*4096 + y*32 + x4
    int x4 = rest & 31;
    int y0 = (rest >> 5) & 127;
    int b  = rest >> 12;
    int x0 = x4 * 4;
    float acc[4][8] = {};
    const us16* inb = in + (size_t)b * LLEN * CC + cg * 8;
    for (int ky = 0; ky < F; ky++) {
        int yy = y0 + ky - P;
        if (yy < 0 || yy > 127) continue;
        const us16* rp = inb + (size_t)yy * WID * CC;
        float rv[NW][8];
        #pragma unroll
        for (int i = 0; i < NW; i++) {
            int xx = x0 - P + i;
            if (xx >= 0 && xx <= 127) {
                bf16x8 v = *(const bf16x8*)(rp + (size_t)xx * CC);
                #pragma unroll
                for (int j = 0; j < 8; j++) rv[i][j] = bf2f((us16)v[j]);
            } else {
                #pragma unroll
                for (int j = 0; j < 8; j++) rv[i][j] = 0.0f;
            }
        }
        #pragma unroll
        for (int kx = 0; kx < F; kx++) {
            bf16x8 wv = *(const bf16x8*)(kws + (ky * F + kx) * CC + cg * 8);
            float w[8];
            #pragma unroll
            for (int j = 0; j < 8; j++) w[j] = bf2f((us16)wv[j]);
            #pragma unroll
            for (int px = 0; px < 4; px++)
                #pragma unroll
                for (int j = 0; j < 8; j++)
                    acc[px][j] += rv[kx + px][j] * w[j];
        }
    }
    int pix = (b * HGT + y0) * WID + x0;
    size_t obase = (size_t)pix * CC + cg * 8;
    #pragma unroll
    for (int px = 0; px < 4; px++) {
        float gl = bf2f(gates[(size_t)(pix + px) * 4 + lvl]);
        bf16x8 cv;
        if (!FIRST) cv = *(const bf16x8*)(ctx_all + obase + (size_t)px * CC);
        bf16x8 ov, cs;
        #pragma unroll
        for (int j = 0; j < 8; j++) {
            float val = gelu_f(acc[px][j]);
            ov[j] = (short)f2bf(val);
            float contrib = val * gl + (FIRST ? 0.0f : bf2f((us16)cv[j]));
            cs[j] = (short)f2bf(contrib);
        }
        *(bf16x8*)(outp   + obase + (size_t)px * CC) = ov;
        *(bf16x8*)(ctx_all + obase + (size_t)px * CC) = cs;
    }
}

// ---------------- Global mean stage 1 ----------
__global__ __launch_bounds__(192) void gmean1_kernel(const us16* __restrict__ ctx,
                                                     float* __restrict__ partial) {
    int blk = blockIdx.x;           // 0..1023
    int b = blk >> 7, chunk = blk & 127;
    int c = threadIdx.x;
    size_t base = ((size_t)b * LLEN + (size_t)chunk * 128) * CC + c;
    float s = 0.0f;
    for (int p = 0; p < 128; p++) s += bf2f(ctx[base + (size_t)p * CC]);
    partial[(size_t)blk * CC + c] = s;
}

// ---------------- Global mean stage 2 + hg = h_w @ gelu(mean) ------------------
__global__ __launch_bounds__(256) void gmean2_kernel(const float* __restrict__ partial,
                                                     const float* __restrict__ h_w,
                                                     float* __restrict__ hg) {
    __shared__ float ctxg[BB * CC];
    for (int t = threadIdx.x; t < BB * CC; t += 256) {
        int b = t / CC, c = t % CC;
        float s = 0.0f;
        for (int p = 0; p < 128; p++) s += partial[(size_t)(b * 128 + p) * CC + c];
        ctxg[t] = gelu_f(s * (1.0f / 16384.0f));
    }
    __syncthreads();
    for (int t = threadIdx.x; t < BB * CC; t += 256) {
        int b = t / CC, o = t % CC;
        float s = 0.0f;
        for (int c2 = 0; c2 < CC; c2++) s += h_w[o * CC + c2] * ctxg[b * CC + c2];
        hg[t] = s;
    }
}

extern "C" void kernel_launch(void* const* d_in, const int* in_sizes, int n_in,
                              void* d_out, int out_size, void* d_ws, size_t ws_size,
                              hipStream_t stream) {
    const float* x      = (const float*)d_in[0];
    const float* ln1_g  = (const float*)d_in[1];
    const float* ln1_b  = (const float*)d_in[2];
    const float* f_w    = (const float*)d_in[3];
    const float* f_b    = (const float*)d_in[4];
    const float* fk0    = (const float*)d_in[5];
    const float* fk1    = (const float*)d_in[6];
    const float* fk2    = (const float*)d_in[7];
    const float* h_w    = (const float*)d_in[8];
    const float* h_b    = (const float*)d_in[9];
    const float* proj_w = (const float*)d_in[10];
    const float* proj_b = (const float*)d_in[11];
    const float* ln2_g  = (const float*)d_in[12];
    const float* ln2_b  = (const float*)d_in[13];
    const float* fc1_w  = (const float*)d_in[14];
    const float* fc1_b  = (const float*)d_in[15];
    const float* fc2_w  = (const float*)d_in[16];
    const float* fc2_b  = (const float*)d_in[17];
    float* outp = (float*)d_out;

    char* ws = (char*)d_ws;
    const size_t S = (size_t)MM * CC * 2;          // 50,331,648 B (one bf16 plane)
    us16* t_buf   = (us16*)(ws);                   // t / xq ; later hid plane 0
    us16* q_buf   = (us16*)(ws + S);               // q ; later ln2 output
    us16* ctx_all = (us16*)(ws + 2 * S);           // ctx_all ; later hid plane 1
    us16* gates   = (us16*)(ws + 3 * S);
    float* partial = (float*)(ws + 3 * S + 1048576);
    float* hg      = partial + 1024 * CC;
    us16* fwT   = (us16*)(ws + 3 * S + 1048576 + 786432 + 6144);
    us16* hwB   = fwT + 86016;
    us16* projT = hwB + 36864;
    us16* w1T   = projT + 36864;
    us16* w2T   = w1T + 147456;
    us16* kw0T  = w2T + 147456;
    us16* kw1T  = kw0T + 1728;
    us16* kw2T  = kw1T + 4800;
    // conv ping-pong lives in d_out (dead until proj rewrites it fully)
    us16* ctxA = (us16*)d_out;
    us16* ctxB = (us16*)d_out + (size_t)MM * CC;

    wcvt_kernel<<<1839, 256, 0, stream>>>(f_w, h_w, proj_w, fc1_w, fc2_w,
                                          fk0, fk1, fk2,
                                          fwT, hwB, projT, w1T, w2T, kw0T, kw1T, kw2T);

    ln_kernel<<<MM / 4, 256, 0, stream>>>(x, ln1_g, ln1_b, t_buf);

    mgemm_kernel<0><<<8 * 128 * 7, 256, 0, stream>>>(
        t_buf, fwT, f_b, q_buf, ctxA, gates, nullptr, nullptr, nullptr, nullptr, nullptr);

    const int convGrid = (MM / 4) * 24 / 256;      // 3072
    convv_kernel<3, true ><<<convGrid, 256, 0, stream>>>(ctxA, ctxB, ctx_all, gates, kw0T, 0);
    convv_kernel<5, false><<<convGrid, 256, 0, stream>>>(ctxB, ctxA, ctx_all, gates, kw1T, 1);
    convv_kernel<7, false><<<convGrid, 256, 0, stream>>>(ctxA, ctxB, ctx_all, gates, kw2T, 2);

    gmean1_kernel<<<1024, 192, 0, stream>>>(ctxB, partial);
    gmean2_kernel<<<1, 256, 0, stream>>>(partial, h_w, hg);

    mgemm_kernel<1><<<8 * 128 * 3, 256, 0, stream>>>(
        ctx_all, hwB, h_b, t_buf, nullptr, nullptr, q_buf, gates, hg, nullptr, nullptr);

    mgemm_kernel<2><<<8 * 128 * 3, 256, 0, stream>>>(
        t_buf, projT, proj_b, nullptr, nullptr, nullptr, nullptr, nullptr, nullptr, x, outp);

    // ---- MLP as two staged GEMMs over two M-halves ----
    ln_kernel<<<MM / 4, 256, 0, stream>>>(outp, ln2_g, ln2_b, q_buf);

    for (int h = 0; h < 2; h++) {
        const us16* Ah = q_buf + (size_t)h * 65536 * CC;
        float* ioh     = outp  + (size_t)h * 65536 * CC;
        fc1_kernel<<<dim3(512, 6), 512, 0, stream>>>(Ah, w1T, fc1_b, t_buf, ctx_all);
        fc2_kernel<<<512, 512, 0, stream>>>(t_buf, ctx_all, w2T, fc2_b, ioh);
    }
}